// Round 1
// baseline (1121.147 us; speedup 1.0000x reference)
//
#include <hip/hip_runtime.h>
#include <math.h>

// Problem constants (B=8, S=512, T=4, D=128)
constexpr int Bdim = 8, Sdim = 512, Tdim = 4, Ddim = 128;
constexpr int M     = Bdim * Sdim * Tdim;          // 16384 keys
constexpr int NANCH = Bdim * Sdim * (Tdim - 1);    // 12288 anchors
constexpr int ELEM  = Bdim * Sdim * Tdim * Ddim;   // 2097152

// ws layout (floats):
// [0]=spike_sum [1]=memsq_sum [2]=ce_sum [3]=nvalid
// [8 .. 8+M)          scale[m] = 10 / max(||h_m||, 1e-12)   (temp folded in)
// [8+M .. 8+M+NANCH)  sumexp[i] = sum_j exp(sim_ij - M_i)
constexpr int WS_FLOATS = 8 + M + NANCH;

__device__ inline float waveRedSum(float v) {
#pragma unroll
  for (int off = 32; off > 0; off >>= 1) v += __shfl_down(v, off, 64);
  return v;
}

// ---------------- K0: spikes mean + mem^2 mean ----------------
__global__ void k_reg(const float* __restrict__ spikes,
                      const float* __restrict__ mem,
                      float* __restrict__ accum) {
  int tid = blockIdx.x * blockDim.x + threadIdx.x;
  int nthreads = gridDim.x * blockDim.x;
  const float4* s4 = (const float4*)spikes;
  const float4* m4 = (const float4*)mem;
  int n4 = ELEM / 4;
  float ssp = 0.f, smem = 0.f;
  for (int i = tid; i < n4; i += nthreads) {
    float4 a = s4[i];
    ssp += a.x + a.y + a.z + a.w;
    float4 b = m4[i];
    smem += b.x * b.x + b.y * b.y + b.z * b.z + b.w * b.w;
  }
  ssp = waveRedSum(ssp);
  smem = waveRedSum(smem);
  __shared__ float buf[2][4];
  int wid = threadIdx.x >> 6, lane = threadIdx.x & 63;
  if (lane == 0) { buf[0][wid] = ssp; buf[1][wid] = smem; }
  __syncthreads();
  if (threadIdx.x == 0) {
    atomicAdd(&accum[0], buf[0][0] + buf[0][1] + buf[0][2] + buf[0][3]);
    atomicAdd(&accum[1], buf[1][0] + buf[1][1] + buf[1][2] + buf[1][3]);
  }
}

// ---------------- K1: per-key scale = 10 / max(||h||,1e-12) ----------------
__global__ void k_norm(const float* __restrict__ H, float* __restrict__ scale) {
  int row = blockIdx.x * 4 + (threadIdx.x >> 6);
  int lane = threadIdx.x & 63;
  float2 v = *(const float2*)(H + (size_t)row * Ddim + lane * 2);
  float ss = v.x * v.x + v.y * v.y;
  ss = waveRedSum(ss);
  if (lane == 0) scale[row] = 10.0f / fmaxf(sqrtf(ss), 1e-12f);
}

// ---------------- K2: fused sim-GEMM + sum-exp ----------------
// Tile: 64 anchors x 64 keys, outer-product micro-tile 4x4 per thread.
// Both operands staged d-major in LDS; scale (incl. 1/temp) folded into keys.
constexpr int BM = 64, BK = 64, KSPLIT = 8;
constexpr int KEYS_PER_BLOCK = M / KSPLIT;  // 2048

__global__ __launch_bounds__(256, 2) void k_sim(const float* __restrict__ H,
                                                const float* __restrict__ scale,
                                                float* __restrict__ sumexp) {
  __shared__ float At[128 * 64];  // [d][anchor]
  __shared__ float Kt[128 * 64];  // [d][key]
  int tid = threadIdx.x;
  int tx = tid & 15;   // anchor subtile (4 anchors: 4*tx..4*tx+3)
  int ty = tid >> 4;   // key subtile    (4 keys:    4*ty..4*ty+3)
  int a0 = blockIdx.y * BM;
  int kbase0 = blockIdx.x * KEYS_PER_BLOCK;

  // Stage A transposed (once per block)
#pragma unroll
  for (int it = 0; it < 8; ++it) {
    int fid = it * 256 + tid;
    int anchor = fid & 63;
    int d4 = fid >> 6;  // 0..31
    int ga = a0 + anchor;
    int row = (ga / 3) * 4 + (ga % 3);  // anchor -> full_hiddens flat row
    float4 v = *(const float4*)(H + (size_t)row * 128 + d4 * 4);
    At[(d4 * 4 + 0) * 64 + anchor] = v.x;
    At[(d4 * 4 + 1) * 64 + anchor] = v.y;
    At[(d4 * 4 + 2) * 64 + anchor] = v.z;
    At[(d4 * 4 + 3) * 64 + anchor] = v.w;
  }

  // M_i = 10*||a_i|| = 100 / scale[row(a_i)]
  float Mi[4];
#pragma unroll
  for (int i = 0; i < 4; ++i) {
    int ga = a0 + 4 * tx + i;
    int row = (ga / 3) * 4 + (ga % 3);
    Mi[i] = 100.0f / scale[row];
  }

  float p[4] = {0.f, 0.f, 0.f, 0.f};
  for (int kc = 0; kc < KEYS_PER_BLOCK; kc += BK) {
    int kbase = kbase0 + kc;
    __syncthreads();
    // Stage K transposed, scale folded in
#pragma unroll
    for (int it = 0; it < 8; ++it) {
      int fid = it * 256 + tid;
      int key = fid & 63;
      int d4 = fid >> 6;
      float sc = scale[kbase + key];
      float4 v = *(const float4*)(H + (size_t)(kbase + key) * 128 + d4 * 4);
      Kt[(d4 * 4 + 0) * 64 + key] = v.x * sc;
      Kt[(d4 * 4 + 1) * 64 + key] = v.y * sc;
      Kt[(d4 * 4 + 2) * 64 + key] = v.z * sc;
      Kt[(d4 * 4 + 3) * 64 + key] = v.w * sc;
    }
    __syncthreads();

    float acc[4][4] = {};
#pragma unroll 4
    for (int d = 0; d < 128; ++d) {
      float4 av = *(const float4*)(At + d * 64 + 4 * tx);
      float4 kv = *(const float4*)(Kt + d * 64 + 4 * ty);
      acc[0][0] += av.x * kv.x; acc[0][1] += av.x * kv.y;
      acc[0][2] += av.x * kv.z; acc[0][3] += av.x * kv.w;
      acc[1][0] += av.y * kv.x; acc[1][1] += av.y * kv.y;
      acc[1][2] += av.y * kv.z; acc[1][3] += av.y * kv.w;
      acc[2][0] += av.z * kv.x; acc[2][1] += av.z * kv.y;
      acc[2][2] += av.z * kv.z; acc[2][3] += av.z * kv.w;
      acc[3][0] += av.w * kv.x; acc[3][1] += av.w * kv.y;
      acc[3][2] += av.w * kv.z; acc[3][3] += av.w * kv.w;
    }
#pragma unroll
    for (int i = 0; i < 4; ++i) {
#pragma unroll
      for (int j = 0; j < 4; ++j) p[i] += __expf(acc[i][j] - Mi[i]);
    }
  }

  // Block-level reduce over the 16 ty strips, one atomic per anchor
  __syncthreads();
  float* red = Kt;  // reuse
#pragma unroll
  for (int i = 0; i < 4; ++i) red[ty * 64 + 4 * tx + i] = p[i];
  __syncthreads();
  if (tid < 64) {
    float s = 0.f;
#pragma unroll
    for (int y = 0; y < 16; ++y) s += red[y * 64 + tid];
    atomicAdd(&sumexp[a0 + tid], s);
  }
}

// ---------------- K3: diagonal + ce masked sum ----------------
__global__ void k_fin(const float* __restrict__ H,
                      const float* __restrict__ scale,
                      const float* __restrict__ sumexp,
                      const int* __restrict__ targets,
                      float* __restrict__ accum) {
  int i = blockIdx.x * 4 + (threadIdx.x >> 6);  // anchor index 0..NANCH-1
  int lane = threadIdx.x & 63;
  int arow = (i / 3) * 4 + (i % 3);
  float2 a = *(const float2*)(H + (size_t)arow * 128 + lane * 2);
  float2 k = *(const float2*)(H + (size_t)i * 128 + lane * 2);  // key j == i
  float d = a.x * k.x + a.y * k.y;
  d = waveRedSum(d);
  if (lane == 0) {
    float sim_ii = d * scale[i];
    float Mi = 100.0f / scale[arow];
    float ce = Mi + __logf(sumexp[i]) - sim_ii;
    if (targets[i / 3] != 0) {
      atomicAdd(&accum[2], ce);
      atomicAdd(&accum[3], 1.0f);
    }
  }
}

// ---------------- K4: final 5 outputs ----------------
__global__ void k_out(const float* __restrict__ accum, float* __restrict__ out) {
  if (threadIdx.x == 0) {
    float spike_rate = accum[0] / (float)ELEM;
    float dr = spike_rate - 0.02f;
    float spike_reg = dr * dr;
    float mem_reg = accum[1] / (float)ELEM;
    float nv = fmaxf(accum[3], 1.0f);
    float tcl = accum[2] / nv;
    float total = tcl + 0.01f * spike_reg + 0.001f * mem_reg;
    out[0] = total;
    out[1] = tcl;
    out[2] = spike_reg;
    out[3] = mem_reg;
    out[4] = spike_rate;
  }
}

extern "C" void kernel_launch(void* const* d_in, const int* in_sizes, int n_in,
                              void* d_out, int out_size, void* d_ws, size_t ws_size,
                              hipStream_t stream) {
  const float* H = (const float*)d_in[0];        // full_hiddens [B,S,T,D]
  const int* targets = (const int*)d_in[1];      // [B,S]
  const float* spikes = (const float*)d_in[2];   // [B,S,T,D]
  const float* mem = (const float*)d_in[3];      // [B,S,T,D]
  float* out = (float*)d_out;
  float* ws = (float*)d_ws;
  float* accum = ws;
  float* scale = ws + 8;
  float* sumexp = ws + 8 + M;

  hipMemsetAsync(d_ws, 0, WS_FLOATS * sizeof(float), stream);
  k_reg<<<1024, 256, 0, stream>>>(spikes, mem, accum);
  k_norm<<<M / 4, 256, 0, stream>>>(H, scale);
  dim3 g2(KSPLIT, NANCH / BM);
  k_sim<<<g2, 256, 0, stream>>>(H, scale, sumexp);
  k_fin<<<NANCH / 4, 256, 0, stream>>>(H, scale, sumexp, targets, accum);
  k_out<<<1, 64, 0, stream>>>(accum, out);
}

// Round 2
// 526.253 us; speedup vs baseline: 2.1304x; 2.1304x over previous
//
#include <hip/hip_runtime.h>
#include <math.h>

// Problem constants (B=8, S=512, T=4, D=128)
constexpr int Bdim = 8, Sdim = 512, Tdim = 4, Ddim = 128;
constexpr int M     = Bdim * Sdim * Tdim;          // 16384 keys
constexpr int NANCH = Bdim * Sdim * (Tdim - 1);    // 12288 anchors
constexpr int ELEM  = Bdim * Sdim * Tdim * Ddim;   // 2097152

// ws layout:
// float accum[8]          : [0]=spike_sum [1]=memsq_sum [2]=ce_sum [3]=nvalid
// float sumexp[NANCH]     : sum_j exp(sim_ij - M_i)
// float scale[M]          : 10 / max(||h_m||, 1e-12)  (temperature folded)
// float MiL[NANCH]        : M_i * log2(e)
// ushort Kbf[M*128]       : bf16(H * scale)  (normalized keys /temp)
// ushort Abf[NANCH*128]   : bf16(H[anchor rows]) (unnormalized)

typedef __bf16 bf16x8 __attribute__((ext_vector_type(8)));
typedef float f32x4 __attribute__((ext_vector_type(4)));

__device__ inline float waveRedSum(float v) {
#pragma unroll
  for (int off = 32; off > 0; off >>= 1) v += __shfl_down(v, off, 64);
  return v;
}

__device__ inline unsigned short f2bf(float x) {  // RNE
  unsigned int u = __float_as_uint(x);
  u += 0x7FFF + ((u >> 16) & 1);
  return (unsigned short)(u >> 16);
}

__device__ inline float fast_exp2(float x) {  // v_exp_f32: 2^x
  float r;
  asm("v_exp_f32 %0, %1" : "=v"(r) : "v"(x));
  return r;
}

// ---------------- K0: spikes mean + mem^2 mean ----------------
__global__ void k_reg(const float* __restrict__ spikes,
                      const float* __restrict__ mem,
                      float* __restrict__ accum) {
  int tid = blockIdx.x * blockDim.x + threadIdx.x;
  int nthreads = gridDim.x * blockDim.x;
  const float4* s4 = (const float4*)spikes;
  const float4* m4 = (const float4*)mem;
  int n4 = ELEM / 4;
  float ssp = 0.f, smem = 0.f;
  for (int i = tid; i < n4; i += nthreads) {
    float4 a = s4[i];
    ssp += a.x + a.y + a.z + a.w;
    float4 b = m4[i];
    smem += b.x * b.x + b.y * b.y + b.z * b.z + b.w * b.w;
  }
  ssp = waveRedSum(ssp);
  smem = waveRedSum(smem);
  __shared__ float buf[2][4];
  int wid = threadIdx.x >> 6, lane = threadIdx.x & 63;
  if (lane == 0) { buf[0][wid] = ssp; buf[1][wid] = smem; }
  __syncthreads();
  if (threadIdx.x == 0) {
    atomicAdd(&accum[0], buf[0][0] + buf[0][1] + buf[0][2] + buf[0][3]);
    atomicAdd(&accum[1], buf[1][0] + buf[1][1] + buf[1][2] + buf[1][3]);
  }
}

// ---------------- K1: per-key scale = 10 / max(||h||,1e-12) ----------------
__global__ void k_norm(const float* __restrict__ H, float* __restrict__ scale) {
  int row = blockIdx.x * 4 + (threadIdx.x >> 6);
  int lane = threadIdx.x & 63;
  float2 v = *(const float2*)(H + (size_t)row * Ddim + lane * 2);
  float ss = v.x * v.x + v.y * v.y;
  ss = waveRedSum(ss);
  if (lane == 0) scale[row] = 10.0f / fmaxf(sqrtf(ss), 1e-12f);
}

// ---------------- K2: fp32 -> bf16 conversion (+ MiL) ----------------
__global__ void k_cvt(const float* __restrict__ H, const float* __restrict__ scale,
                      unsigned short* __restrict__ Kbf, unsigned short* __restrict__ Abf,
                      float* __restrict__ MiL) {
  int tid = blockIdx.x * blockDim.x + threadIdx.x;  // one per 4 elements
  int nK4 = M * 32;                                  // 524288
  if (tid < nK4) {
    int r = tid >> 5;
    float sc = scale[r];
    float4 v = ((const float4*)H)[tid];
    ushort4 o;
    o.x = f2bf(v.x * sc); o.y = f2bf(v.y * sc);
    o.z = f2bf(v.z * sc); o.w = f2bf(v.w * sc);
    ((ushort4*)Kbf)[tid] = o;
  } else {
    int t2 = tid - nK4;
    if (t2 < NANCH * 32) {
      int i = t2 >> 5, dc = t2 & 31;
      int row = (i / 3) * 4 + (i % 3);
      float4 v = ((const float4*)H)[row * 32 + dc];
      ushort4 o;
      o.x = f2bf(v.x); o.y = f2bf(v.y); o.z = f2bf(v.z); o.w = f2bf(v.w);
      ((ushort4*)Abf)[t2] = o;
      if (dc == 0) MiL[i] = 144.269504088896f / scale[row];  // (100/scale)*log2e
    }
  }
}

// ---------------- K3: MFMA sim-GEMM + fused exp + row-sum ----------------
// 128 anchors x 128 keys per tile; 4 waves in 2x2; 16x16x32 bf16 MFMA.
// LDS tiles stored row-major in 16B chunks with XOR swizzle (conflict-free).
constexpr int KSPLIT = 16;
constexpr int KEYS_PB = M / KSPLIT;   // 1024 keys per block
constexpr int NT = KEYS_PB / 128;     // 8 key tiles

__global__ __launch_bounds__(256, 2) void k_sim(
    const unsigned short* __restrict__ Abf, const unsigned short* __restrict__ Kbf,
    const float* __restrict__ MiL, float* __restrict__ sumexp) {
  __shared__ unsigned short At[128 * 128];
  __shared__ unsigned short Kt[128 * 128];
  const int tid = threadIdx.x;
  const int lane = tid & 63;
  const int w = tid >> 6;
  const int wm = (w & 1) * 64, wn = (w >> 1) * 64;
  const int a0 = blockIdx.y * 128;
  const int k0 = blockIdx.x * KEYS_PB;
  const int rquad = (lane >> 4) * 4;
  const int lcol = lane & 15;

  // stage A tile (once per block)
  {
    const uint4* src = (const uint4*)(Abf + (size_t)a0 * 128);
    uint4* dst = (uint4*)At;
#pragma unroll
    for (int it = 0; it < 8; ++it) {
      int fid = it * 256 + tid;
      int row = fid >> 4, chunk = fid & 15;
      dst[row * 16 + (chunk ^ (row & 7))] = src[fid];
    }
  }

  // preload MiL for my 16 anchor rows
  float miL[4][4];
#pragma unroll
  for (int mi = 0; mi < 4; ++mi)
#pragma unroll
    for (int r = 0; r < 4; ++r)
      miL[mi][r] = MiL[a0 + wm + mi * 16 + rquad + r];

  float rs[4][4] = {};

  for (int t = 0; t < NT; ++t) {
    const uint4* src = (const uint4*)(Kbf + (size_t)(k0 + t * 128) * 128);
    uint4* dst = (uint4*)Kt;
    __syncthreads();
#pragma unroll
    for (int it = 0; it < 8; ++it) {
      int fid = it * 256 + tid;
      int row = fid >> 4, chunk = fid & 15;
      dst[row * 16 + (chunk ^ (row & 7))] = src[fid];
    }
    __syncthreads();

    f32x4 acc[4][4] = {};
#pragma unroll
    for (int ks = 0; ks < 4; ++ks) {
      bf16x8 af[4], bfr[4];
      int chunk = ks * 4 + (lane >> 4);
#pragma unroll
      for (int mi = 0; mi < 4; ++mi) {
        int r = wm + mi * 16 + lcol;
        af[mi] = *(const bf16x8*)(At + (r * 16 + (chunk ^ (r & 7))) * 8);
      }
#pragma unroll
      for (int nj = 0; nj < 4; ++nj) {
        int r = wn + nj * 16 + lcol;
        bfr[nj] = *(const bf16x8*)(Kt + (r * 16 + (chunk ^ (r & 7))) * 8);
      }
#pragma unroll
      for (int mi = 0; mi < 4; ++mi)
#pragma unroll
        for (int nj = 0; nj < 4; ++nj)
          acc[mi][nj] = __builtin_amdgcn_mfma_f32_16x16x32_bf16(af[mi], bfr[nj], acc[mi][nj], 0, 0, 0);
    }

    // fused epilogue: rs += 2^(sim*log2e - Mi*log2e)
#pragma unroll
    for (int mi = 0; mi < 4; ++mi)
#pragma unroll
      for (int nj = 0; nj < 4; ++nj)
#pragma unroll
        for (int r = 0; r < 4; ++r)
          rs[mi][r] += fast_exp2(fmaf(acc[mi][nj][r], 1.44269504088896f, -miL[mi][r]));
  }

  // reduce over 16 columns (lanes sharing lane>>4), one atomic per anchor
#pragma unroll
  for (int mi = 0; mi < 4; ++mi)
#pragma unroll
    for (int r = 0; r < 4; ++r) {
      float v = rs[mi][r];
      v += __shfl_xor(v, 1, 64);
      v += __shfl_xor(v, 2, 64);
      v += __shfl_xor(v, 4, 64);
      v += __shfl_xor(v, 8, 64);
      if (lcol == 0) atomicAdd(&sumexp[a0 + wm + mi * 16 + rquad + r], v);
    }
}

// ---------------- K4: diagonal (fp32) + ce masked sum ----------------
__global__ void k_fin(const float* __restrict__ H,
                      const float* __restrict__ scale,
                      const float* __restrict__ sumexp,
                      const int* __restrict__ targets,
                      float* __restrict__ accum) {
  int i = blockIdx.x * 4 + (threadIdx.x >> 6);
  int lane = threadIdx.x & 63;
  int arow = (i / 3) * 4 + (i % 3);
  float2 a = *(const float2*)(H + (size_t)arow * 128 + lane * 2);
  float2 k = *(const float2*)(H + (size_t)i * 128 + lane * 2);
  float d = a.x * k.x + a.y * k.y;
  d = waveRedSum(d);
  if (lane == 0) {
    float sim_ii = d * scale[i];
    float Mi = 100.0f / scale[arow];
    float ce = Mi + __logf(sumexp[i]) - sim_ii;
    if (targets[i / 3] != 0) {
      atomicAdd(&accum[2], ce);
      atomicAdd(&accum[3], 1.0f);
    }
  }
}

// ---------------- K5: final 5 outputs ----------------
__global__ void k_out(const float* __restrict__ accum, float* __restrict__ out) {
  if (threadIdx.x == 0) {
    float spike_rate = accum[0] / (float)ELEM;
    float dr = spike_rate - 0.02f;
    float spike_reg = dr * dr;
    float mem_reg = accum[1] / (float)ELEM;
    float nv = fmaxf(accum[3], 1.0f);
    float tcl = accum[2] / nv;
    float total = tcl + 0.01f * spike_reg + 0.001f * mem_reg;
    out[0] = total;
    out[1] = tcl;
    out[2] = spike_reg;
    out[3] = mem_reg;
    out[4] = spike_rate;
  }
}

extern "C" void kernel_launch(void* const* d_in, const int* in_sizes, int n_in,
                              void* d_out, int out_size, void* d_ws, size_t ws_size,
                              hipStream_t stream) {
  const float* H = (const float*)d_in[0];
  const int* targets = (const int*)d_in[1];
  const float* spikes = (const float*)d_in[2];
  const float* mem = (const float*)d_in[3];
  float* out = (float*)d_out;
  float* ws = (float*)d_ws;

  float* accum = ws;                    // 8
  float* sumexp = ws + 8;               // NANCH
  float* scale = sumexp + NANCH;        // M
  float* MiL = scale + M;               // NANCH
  unsigned short* Kbf = (unsigned short*)(MiL + NANCH);  // M*128
  unsigned short* Abf = Kbf + (size_t)M * 128;           // NANCH*128

  hipMemsetAsync(d_ws, 0, (8 + NANCH) * sizeof(float), stream);
  k_reg<<<2048, 256, 0, stream>>>(spikes, mem, accum);
  k_norm<<<M / 4, 256, 0, stream>>>(H, scale);
  int cvt_threads = (M + NANCH) * 32;
  k_cvt<<<(cvt_threads + 255) / 256, 256, 0, stream>>>(H, scale, Kbf, Abf, MiL);
  dim3 g2(KSPLIT, NANCH / 128);
  k_sim<<<g2, 256, 0, stream>>>(Abf, Kbf, MiL, sumexp);
  k_fin<<<NANCH / 4, 256, 0, stream>>>(H, scale, sumexp, targets, accum);
  k_out<<<1, 64, 0, stream>>>(accum, out);
}

// Round 3
// 225.089 us; speedup vs baseline: 4.9809x; 2.3380x over previous
//
#include <hip/hip_runtime.h>
#include <math.h>

// Problem constants (B=8, S=512, T=4, D=128)
constexpr int Bdim = 8, Sdim = 512, Tdim = 4, Ddim = 128;
constexpr int M     = Bdim * Sdim * Tdim;          // 16384 keys
constexpr int NANCH = Bdim * Sdim * (Tdim - 1);    // 12288 anchors
constexpr int ELEM  = Bdim * Sdim * Tdim * Ddim;   // 2097152

typedef __bf16 bf16x8 __attribute__((ext_vector_type(8)));
typedef float f32x4 __attribute__((ext_vector_type(4)));

__device__ inline float waveRedSum(float v) {
#pragma unroll
  for (int off = 32; off > 0; off >>= 1) v += __shfl_down(v, off, 64);
  return v;
}

__device__ inline unsigned short f2bf(float x) {  // RNE
  unsigned int u = __float_as_uint(x);
  u += 0x7FFF + ((u >> 16) & 1);
  return (unsigned short)(u >> 16);
}

__device__ inline float fast_exp2(float x) {  // v_exp_f32: 2^x
  float r;
  asm("v_exp_f32 %0, %1" : "=v"(r) : "v"(x));
  return r;
}

// ---------------- K0: spikes mean + mem^2 mean ----------------
__global__ void k_reg(const float* __restrict__ spikes,
                      const float* __restrict__ mem,
                      float* __restrict__ accum) {
  int tid = blockIdx.x * blockDim.x + threadIdx.x;
  int nthreads = gridDim.x * blockDim.x;
  const float4* s4 = (const float4*)spikes;
  const float4* m4 = (const float4*)mem;
  int n4 = ELEM / 4;
  float ssp = 0.f, smem = 0.f;
  for (int i = tid; i < n4; i += nthreads) {
    float4 a = s4[i];
    ssp += a.x + a.y + a.z + a.w;
    float4 b = m4[i];
    smem += b.x * b.x + b.y * b.y + b.z * b.z + b.w * b.w;
  }
  ssp = waveRedSum(ssp);
  smem = waveRedSum(smem);
  __shared__ float buf[2][4];
  int wid = threadIdx.x >> 6, lane = threadIdx.x & 63;
  if (lane == 0) { buf[0][wid] = ssp; buf[1][wid] = smem; }
  __syncthreads();
  if (threadIdx.x == 0) {
    atomicAdd(&accum[0], buf[0][0] + buf[0][1] + buf[0][2] + buf[0][3]);
    atomicAdd(&accum[1], buf[1][0] + buf[1][1] + buf[1][2] + buf[1][3]);
  }
}

// ---------------- K1: per-key scale = 10 / max(||h||,1e-12) ----------------
__global__ void k_norm(const float* __restrict__ H, float* __restrict__ scale) {
  int row = blockIdx.x * 4 + (threadIdx.x >> 6);
  int lane = threadIdx.x & 63;
  float2 v = *(const float2*)(H + (size_t)row * Ddim + lane * 2);
  float ss = v.x * v.x + v.y * v.y;
  ss = waveRedSum(ss);
  if (lane == 0) scale[row] = 10.0f / fmaxf(sqrtf(ss), 1e-12f);
}

// ---------------- K2: fp32 -> bf16 conversion (+ MiL) ----------------
__global__ void k_cvt(const float* __restrict__ H, const float* __restrict__ scale,
                      unsigned short* __restrict__ Kbf, unsigned short* __restrict__ Abf,
                      float* __restrict__ MiL) {
  int tid = blockIdx.x * blockDim.x + threadIdx.x;  // one per 4 elements
  int nK4 = M * 32;                                  // 524288
  if (tid < nK4) {
    int r = tid >> 5;
    float sc = scale[r];
    float4 v = ((const float4*)H)[tid];
    ushort4 o;
    o.x = f2bf(v.x * sc); o.y = f2bf(v.y * sc);
    o.z = f2bf(v.z * sc); o.w = f2bf(v.w * sc);
    ((ushort4*)Kbf)[tid] = o;
  } else {
    int t2 = tid - nK4;
    if (t2 < NANCH * 32) {
      int i = t2 >> 5, dc = t2 & 31;
      int row = (i / 3) * 4 + (i % 3);
      float4 v = ((const float4*)H)[row * 32 + dc];
      ushort4 o;
      o.x = f2bf(v.x); o.y = f2bf(v.y); o.z = f2bf(v.z); o.w = f2bf(v.w);
      ((ushort4*)Abf)[t2] = o;
      if (dc == 0) MiL[i] = 144.269504088896f / scale[row];  // (100/scale)*log2e
    }
  }
}

// ---------------- K3: MFMA sim-GEMM + fused exp + row-sum ----------------
// 128 anchors x 128 keys per tile; 4 waves in 2x2; 16x16x32 bf16 MFMA.
// LDS tiles stored row-major in 16B chunks with XOR swizzle (conflict-free).
constexpr int KSPLIT = 16;
constexpr int KEYS_PB = M / KSPLIT;   // 1024 keys per block
constexpr int NT = KEYS_PB / 128;     // 8 key tiles

__global__ __launch_bounds__(256, 2) void k_sim(
    const unsigned short* __restrict__ Abf, const unsigned short* __restrict__ Kbf,
    const float* __restrict__ MiL, float* __restrict__ sumexp) {
  __shared__ unsigned short At[128 * 128];
  __shared__ unsigned short Kt[128 * 128];
  const int tid = threadIdx.x;
  const int lane = tid & 63;
  const int w = tid >> 6;
  const int wm = (w & 1) * 64, wn = (w >> 1) * 64;
  const int a0 = blockIdx.y * 128;
  const int k0 = blockIdx.x * KEYS_PB;
  const int rquad = (lane >> 4) * 4;
  const int lcol = lane & 15;

  // stage A tile (once per block)
  {
    const uint4* src = (const uint4*)(Abf + (size_t)a0 * 128);
    uint4* dst = (uint4*)At;
#pragma unroll
    for (int it = 0; it < 8; ++it) {
      int fid = it * 256 + tid;
      int row = fid >> 4, chunk = fid & 15;
      dst[row * 16 + (chunk ^ (row & 7))] = src[fid];
    }
  }

  // preload MiL for my 16 anchor rows
  float miL[4][4];
#pragma unroll
  for (int mi = 0; mi < 4; ++mi)
#pragma unroll
    for (int r = 0; r < 4; ++r)
      miL[mi][r] = MiL[a0 + wm + mi * 16 + rquad + r];

  float rs[4][4] = {};

  for (int t = 0; t < NT; ++t) {
    const uint4* src = (const uint4*)(Kbf + (size_t)(k0 + t * 128) * 128);
    uint4* dst = (uint4*)Kt;
    __syncthreads();
#pragma unroll
    for (int it = 0; it < 8; ++it) {
      int fid = it * 256 + tid;
      int row = fid >> 4, chunk = fid & 15;
      dst[row * 16 + (chunk ^ (row & 7))] = src[fid];
    }
    __syncthreads();

    f32x4 acc[4][4] = {};
#pragma unroll
    for (int ks = 0; ks < 4; ++ks) {
      bf16x8 af[4], bfr[4];
      int chunk = ks * 4 + (lane >> 4);
#pragma unroll
      for (int mi = 0; mi < 4; ++mi) {
        int r = wm + mi * 16 + lcol;
        af[mi] = *(const bf16x8*)(At + (r * 16 + (chunk ^ (r & 7))) * 8);
      }
#pragma unroll
      for (int nj = 0; nj < 4; ++nj) {
        int r = wn + nj * 16 + lcol;
        bfr[nj] = *(const bf16x8*)(Kt + (r * 16 + (chunk ^ (r & 7))) * 8);
      }
#pragma unroll
      for (int mi = 0; mi < 4; ++mi)
#pragma unroll
        for (int nj = 0; nj < 4; ++nj)
          acc[mi][nj] = __builtin_amdgcn_mfma_f32_16x16x32_bf16(af[mi], bfr[nj], acc[mi][nj], 0, 0, 0);
    }

    // fused epilogue: rs += 2^(sim*log2e - Mi*log2e)
#pragma unroll
    for (int mi = 0; mi < 4; ++mi)
#pragma unroll
      for (int nj = 0; nj < 4; ++nj)
#pragma unroll
        for (int r = 0; r < 4; ++r)
          rs[mi][r] += fast_exp2(fmaf(acc[mi][nj][r], 1.44269504088896f, -miL[mi][r]));
  }

  // reduce over 16 columns (lanes sharing lane>>4), one atomic per anchor
#pragma unroll
  for (int mi = 0; mi < 4; ++mi)
#pragma unroll
    for (int r = 0; r < 4; ++r) {
      float v = rs[mi][r];
      v += __shfl_xor(v, 1, 64);
      v += __shfl_xor(v, 2, 64);
      v += __shfl_xor(v, 4, 64);
      v += __shfl_xor(v, 8, 64);
      if (lcol == 0) atomicAdd(&sumexp[a0 + wm + mi * 16 + rquad + r], v);
    }
}

// ---------------- K4: diagonal (fp32) + ce masked sum ----------------
// 64 anchors per block (4 waves x 16); block-reduce; 2 atomics per BLOCK
// (was 2 per anchor -> 24576 same-address atomics = 315 us serial chain).
__global__ __launch_bounds__(256) void k_fin(
    const float* __restrict__ H, const float* __restrict__ scale,
    const float* __restrict__ sumexp, const int* __restrict__ targets,
    float* __restrict__ accum) {
  int w = threadIdx.x >> 6, lane = threadIdx.x & 63;
  int abase = blockIdx.x * 64 + w * 16;
  float ce_sum = 0.f, nv = 0.f;
#pragma unroll 4
  for (int ii = 0; ii < 16; ++ii) {
    int i = abase + ii;
    int arow = (i / 3) * 4 + (i % 3);
    float2 a = *(const float2*)(H + (size_t)arow * 128 + lane * 2);
    float2 k = *(const float2*)(H + (size_t)i * 128 + lane * 2);
    float d = a.x * k.x + a.y * k.y;
    d = waveRedSum(d);
    if (lane == 0 && targets[i / 3] != 0) {
      float sim_ii = d * scale[i];
      float Mi = 100.0f / scale[arow];
      ce_sum += Mi + __logf(sumexp[i]) - sim_ii;
      nv += 1.0f;
    }
  }
  __shared__ float buf[2][4];
  if (lane == 0) { buf[0][w] = ce_sum; buf[1][w] = nv; }
  __syncthreads();
  if (threadIdx.x == 0) {
    atomicAdd(&accum[2], buf[0][0] + buf[0][1] + buf[0][2] + buf[0][3]);
    atomicAdd(&accum[3], buf[1][0] + buf[1][1] + buf[1][2] + buf[1][3]);
  }
}

// ---------------- K5: final 5 outputs ----------------
__global__ void k_out(const float* __restrict__ accum, float* __restrict__ out) {
  if (threadIdx.x == 0) {
    float spike_rate = accum[0] / (float)ELEM;
    float dr = spike_rate - 0.02f;
    float spike_reg = dr * dr;
    float mem_reg = accum[1] / (float)ELEM;
    float nv = fmaxf(accum[3], 1.0f);
    float tcl = accum[2] / nv;
    float total = tcl + 0.01f * spike_reg + 0.001f * mem_reg;
    out[0] = total;
    out[1] = tcl;
    out[2] = spike_reg;
    out[3] = mem_reg;
    out[4] = spike_rate;
  }
}

extern "C" void kernel_launch(void* const* d_in, const int* in_sizes, int n_in,
                              void* d_out, int out_size, void* d_ws, size_t ws_size,
                              hipStream_t stream) {
  const float* H = (const float*)d_in[0];
  const int* targets = (const int*)d_in[1];
  const float* spikes = (const float*)d_in[2];
  const float* mem = (const float*)d_in[3];
  float* out = (float*)d_out;
  float* ws = (float*)d_ws;

  float* accum = ws;                    // 8
  float* sumexp = ws + 8;               // NANCH
  float* scale = sumexp + NANCH;        // M
  float* MiL = scale + M;               // NANCH
  unsigned short* Kbf = (unsigned short*)(MiL + NANCH);  // M*128
  unsigned short* Abf = Kbf + (size_t)M * 128;           // NANCH*128

  hipMemsetAsync(d_ws, 0, (8 + NANCH) * sizeof(float), stream);
  k_reg<<<2048, 256, 0, stream>>>(spikes, mem, accum);
  k_norm<<<M / 4, 256, 0, stream>>>(H, scale);
  int cvt_threads = (M + NANCH) * 32;
  k_cvt<<<(cvt_threads + 255) / 256, 256, 0, stream>>>(H, scale, Kbf, Abf, MiL);
  dim3 g2(KSPLIT, NANCH / 128);
  k_sim<<<g2, 256, 0, stream>>>(Abf, Kbf, MiL, sumexp);
  k_fin<<<NANCH / 64, 256, 0, stream>>>(H, scale, sumexp, targets, accum);
  k_out<<<1, 64, 0, stream>>>(accum, out);
}

// Round 4
// 154.731 us; speedup vs baseline: 7.2458x; 1.4547x over previous
//
#include <hip/hip_runtime.h>
#include <math.h>

// Problem constants (B=8, S=512, T=4, D=128)
constexpr int Bdim = 8, Sdim = 512, Tdim = 4, Ddim = 128;
constexpr int M     = Bdim * Sdim * Tdim;          // 16384 keys
constexpr int NANCH = Bdim * Sdim * (Tdim - 1);    // 12288 anchors
constexpr int ELEM  = Bdim * Sdim * Tdim * Ddim;   // 2097152

typedef __bf16 bf16x8 __attribute__((ext_vector_type(8)));
typedef float f32x4 __attribute__((ext_vector_type(4)));
typedef unsigned int uint;

__device__ inline float waveRedSum(float v) {
#pragma unroll
  for (int off = 32; off > 0; off >>= 1) v += __shfl_down(v, off, 64);
  return v;
}

__device__ inline unsigned short f2bf(float x) {  // RNE
  unsigned int u = __float_as_uint(x);
  u += 0x7FFF + ((u >> 16) & 1);
  return (unsigned short)(u >> 16);
}

__device__ inline float fast_exp2(float x) {  // v_exp_f32: 2^x
  float r;
  asm("v_exp_f32 %0, %1" : "=v"(r) : "v"(x));
  return r;
}

// async 16B global -> LDS (wave-uniform base + lane*16 semantics)
__device__ inline void load_lds16(uint4* lds, const uint4* g) {
  __builtin_amdgcn_global_load_lds(
      (const __attribute__((address_space(1))) unsigned int*)g,
      (__attribute__((address_space(3))) unsigned int*)lds, 16, 0, 0);
}

// ---------------- K1: fused prep ----------------
// Per row r: ss -> scale; write pre-swizzled bf16 key row (scale folded) and,
// for anchor rows, pre-swizzled bf16 anchor row + MiL. Also spike/mem partials.
// Swizzle: 16B chunk c of row r stored at chunk index (c ^ (r&7)).
__global__ __launch_bounds__(256) void k_prep(
    const float* __restrict__ H, const float* __restrict__ spikes,
    const float* __restrict__ mem, uint* __restrict__ Ksw, uint* __restrict__ Asw,
    float* __restrict__ scale, float* __restrict__ MiL,
    float* __restrict__ Pspike, float* __restrict__ Pmem) {
  int b = blockIdx.x;  // 0..1023
  int tid = threadIdx.x, w = tid >> 6, lane = tid & 63;
#pragma unroll
  for (int j = 0; j < 4; ++j) {
    int r = b * 16 + w * 4 + j;
    float2 v = *(const float2*)(H + (size_t)r * 128 + lane * 2);
    float ss = waveRedSum(v.x * v.x + v.y * v.y);
    float sst = __shfl(ss, 0, 64);
    float sc = 10.0f / fmaxf(sqrtf(sst), 1e-12f);
    if (lane == 0) scale[r] = sc;
    uint kw = ((uint)f2bf(v.y * sc) << 16) | (uint)f2bf(v.x * sc);
    Ksw[r * 64 + (((lane >> 2) ^ (r & 7)) << 2) + (lane & 3)] = kw;
    if ((r & 3) != 3) {
      int i = (r >> 2) * 3 + (r & 3);
      uint aw = ((uint)f2bf(v.y) << 16) | (uint)f2bf(v.x);
      Asw[i * 64 + (((lane >> 2) ^ (i & 7)) << 2) + (lane & 3)] = aw;
      if (lane == 0) MiL[i] = 144.269504088896f / sc;  // (100/sc)*log2e
    }
  }
  // spikes mean + mem^2 partials: 2 float4 per thread per array
  int g = b * 256 + tid;  // 0..262143
  float4 s0 = ((const float4*)spikes)[g];
  float4 s1 = ((const float4*)spikes)[g + 262144];
  float4 m0 = ((const float4*)mem)[g];
  float4 m1 = ((const float4*)mem)[g + 262144];
  float ssp = s0.x + s0.y + s0.z + s0.w + s1.x + s1.y + s1.z + s1.w;
  float smm = m0.x * m0.x + m0.y * m0.y + m0.z * m0.z + m0.w * m0.w +
              m1.x * m1.x + m1.y * m1.y + m1.z * m1.z + m1.w * m1.w;
  ssp = waveRedSum(ssp);
  smm = waveRedSum(smm);
  __shared__ float buf[2][4];
  if (lane == 0) { buf[0][w] = ssp; buf[1][w] = smm; }
  __syncthreads();
  if (tid == 0) {
    Pspike[b] = buf[0][0] + buf[0][1] + buf[0][2] + buf[0][3];
    Pmem[b]   = buf[1][0] + buf[1][1] + buf[1][2] + buf[1][3];
  }
}

// ---------------- K2: MFMA sim-GEMM + fused exp + row-sum ----------------
// 128 anchors x 128 keys per tile; A-fragments in registers; single 32 KB
// LDS buffer for K tiles staged via global_load_lds (pre-swizzled layout).
constexpr int KSPLIT = 16;
constexpr int KEYS_PB = M / KSPLIT;   // 1024 keys per block
constexpr int NT = KEYS_PB / 128;     // 8 key tiles

__global__ __launch_bounds__(256, 2) void k_sim(
    const uint* __restrict__ Ksw, const uint* __restrict__ Asw,
    const float* __restrict__ MiL, float* __restrict__ sumexp) {
  __shared__ uint4 Tile[128 * 16];  // 32 KB
  const int tid = threadIdx.x;
  const int lane = tid & 63;
  const int w = tid >> 6;
  const int wm = (w & 1) * 64, wn = (w >> 1) * 64;
  const int a0 = blockIdx.y * 128;
  const int k0 = blockIdx.x * KEYS_PB;
  const int lcol = lane & 15;
  const int lhi = lane >> 4;

  // stage A tile (pre-swizzled, async), then read my 16 A-fragments to regs
  {
    const uint4* src = (const uint4*)Asw + (size_t)a0 * 16;
#pragma unroll
    for (int it = 0; it < 8; ++it) {
      int fid = it * 256 + tid;
      load_lds16(Tile + fid, src + fid);
    }
  }
  __syncthreads();
  bf16x8 af[4][4];
#pragma unroll
  for (int mi = 0; mi < 4; ++mi) {
    int r = wm + mi * 16 + lcol;
#pragma unroll
    for (int ks = 0; ks < 4; ++ks) {
      int chunk = ks * 4 + lhi;
      af[mi][ks] = *(const bf16x8*)((const unsigned short*)Tile +
                                    ((size_t)r * 16 + (chunk ^ (lcol & 7))) * 8);
    }
  }
  float nmiL[4][4];
#pragma unroll
  for (int mi = 0; mi < 4; ++mi)
#pragma unroll
    for (int r = 0; r < 4; ++r)
      nmiL[mi][r] = -MiL[a0 + wm + mi * 16 + lhi * 4 + r];
  __syncthreads();  // all af reads done before K staging overwrites Tile

  float rs[4][4] = {};
  for (int t = 0; t < NT; ++t) {
    const uint4* src = (const uint4*)Ksw + (size_t)(k0 + t * 128) * 16;
#pragma unroll
    for (int it = 0; it < 8; ++it) {
      int fid = it * 256 + tid;
      load_lds16(Tile + fid, src + fid);
    }
    __syncthreads();  // vmcnt drained by barrier -> LDS image ready

    f32x4 acc[4][4] = {};
#pragma unroll
    for (int ks = 0; ks < 4; ++ks) {
      bf16x8 bfr[4];
      int chunk = ks * 4 + lhi;
#pragma unroll
      for (int nj = 0; nj < 4; ++nj) {
        int r = wn + nj * 16 + lcol;
        bfr[nj] = *(const bf16x8*)((const unsigned short*)Tile +
                                   ((size_t)r * 16 + (chunk ^ (lcol & 7))) * 8);
      }
#pragma unroll
      for (int mi = 0; mi < 4; ++mi)
#pragma unroll
        for (int nj = 0; nj < 4; ++nj)
          acc[mi][nj] = __builtin_amdgcn_mfma_f32_16x16x32_bf16(af[mi][ks], bfr[nj], acc[mi][nj], 0, 0, 0);
    }
    __syncthreads();  // reads done before next tile's staging

    // fused epilogue: rs += 2^(sim*log2e - MiL)   (register-only)
#pragma unroll
    for (int mi = 0; mi < 4; ++mi)
#pragma unroll
      for (int nj = 0; nj < 4; ++nj)
#pragma unroll
        for (int r = 0; r < 4; ++r)
          rs[mi][r] += fast_exp2(fmaf(acc[mi][nj][r], 1.44269504088896f, nmiL[mi][r]));
  }

  // reduce over 16 columns, one atomic per anchor per wave
#pragma unroll
  for (int mi = 0; mi < 4; ++mi)
#pragma unroll
    for (int r = 0; r < 4; ++r) {
      float v = rs[mi][r];
      v += __shfl_xor(v, 1, 64);
      v += __shfl_xor(v, 2, 64);
      v += __shfl_xor(v, 4, 64);
      v += __shfl_xor(v, 8, 64);
      if (lcol == 0) atomicAdd(&sumexp[a0 + wm + mi * 16 + lhi * 4 + r], v);
    }
}

// ---------------- K3: diagonal (fp32) + ce masked partials ----------------
__global__ __launch_bounds__(256) void k_fin(
    const float* __restrict__ H, const float* __restrict__ scale,
    const float* __restrict__ sumexp, const int* __restrict__ targets,
    float* __restrict__ Pce, float* __restrict__ Pnv) {
  int w = threadIdx.x >> 6, lane = threadIdx.x & 63;
  int abase = blockIdx.x * 64 + w * 16;
  float ce_sum = 0.f, nv = 0.f;
#pragma unroll 4
  for (int ii = 0; ii < 16; ++ii) {
    int i = abase + ii;
    int arow = (i / 3) * 4 + (i % 3);
    float2 a = *(const float2*)(H + (size_t)arow * 128 + lane * 2);
    float2 k = *(const float2*)(H + (size_t)i * 128 + lane * 2);
    float d = waveRedSum(a.x * k.x + a.y * k.y);
    if (lane == 0 && targets[i / 3] != 0) {
      float sim_ii = d * scale[i];
      float Mi = 100.0f / scale[arow];
      ce_sum += Mi + __logf(sumexp[i]) - sim_ii;
      nv += 1.0f;
    }
  }
  __shared__ float buf[2][4];
  if (lane == 0) { buf[0][w] = ce_sum; buf[1][w] = nv; }
  __syncthreads();
  if (threadIdx.x == 0) {
    Pce[blockIdx.x] = buf[0][0] + buf[0][1] + buf[0][2] + buf[0][3];
    Pnv[blockIdx.x] = buf[1][0] + buf[1][1] + buf[1][2] + buf[1][3];
  }
}

// ---------------- K4: reduce partials + final 5 outputs ----------------
__global__ void k_out(const float* __restrict__ Pspike, const float* __restrict__ Pmem,
                      const float* __restrict__ Pce, const float* __restrict__ Pnv,
                      float* __restrict__ out) {
  int tid = threadIdx.x, w = tid >> 6, lane = tid & 63;
  float a = 0.f, b = 0.f, c = 0.f, d = 0.f;
  for (int i = tid; i < 1024; i += 256) { a += Pspike[i]; b += Pmem[i]; }
  if (tid < 192) { c = Pce[tid]; d = Pnv[tid]; }
  a = waveRedSum(a); b = waveRedSum(b); c = waveRedSum(c); d = waveRedSum(d);
  __shared__ float buf[4][4];
  if (lane == 0) { buf[0][w] = a; buf[1][w] = b; buf[2][w] = c; buf[3][w] = d; }
  __syncthreads();
  if (tid == 0) {
    float ssp = buf[0][0] + buf[0][1] + buf[0][2] + buf[0][3];
    float smm = buf[1][0] + buf[1][1] + buf[1][2] + buf[1][3];
    float ce  = buf[2][0] + buf[2][1] + buf[2][2] + buf[2][3];
    float nv  = buf[3][0] + buf[3][1] + buf[3][2] + buf[3][3];
    float spike_rate = ssp / (float)ELEM;
    float dr = spike_rate - 0.02f;
    float spike_reg = dr * dr;
    float mem_reg = smm / (float)ELEM;
    float tcl = ce / fmaxf(nv, 1.0f);
    out[0] = tcl + 0.01f * spike_reg + 0.001f * mem_reg;
    out[1] = tcl;
    out[2] = spike_reg;
    out[3] = mem_reg;
    out[4] = spike_rate;
  }
}

extern "C" void kernel_launch(void* const* d_in, const int* in_sizes, int n_in,
                              void* d_out, int out_size, void* d_ws, size_t ws_size,
                              hipStream_t stream) {
  const float* H = (const float*)d_in[0];
  const int* targets = (const int*)d_in[1];
  const float* spikes = (const float*)d_in[2];
  const float* mem = (const float*)d_in[3];
  float* out = (float*)d_out;
  float* ws = (float*)d_ws;

  float* sumexp = ws;                    // 12288
  float* scale  = ws + 12288;            // 16384
  float* MiL    = ws + 28672;            // 12288
  float* Pspike = ws + 40960;            // 1024
  float* Pmem   = ws + 41984;            // 1024
  float* Pce    = ws + 43008;            // 192
  float* Pnv    = ws + 43200;            // 192
  uint*  Ksw    = (uint*)(ws + 43392);   // M*64 uints (16B-aligned)
  uint*  Asw    = Ksw + (size_t)M * 64;  // NANCH*64 uints

  hipMemsetAsync(sumexp, 0, NANCH * sizeof(float), stream);
  k_prep<<<1024, 256, 0, stream>>>(H, spikes, mem, Ksw, Asw, scale, MiL, Pspike, Pmem);
  dim3 g2(KSPLIT, NANCH / 128);
  k_sim<<<g2, 256, 0, stream>>>(Ksw, Asw, MiL, sumexp);
  k_fin<<<NANCH / 64, 256, 0, stream>>>(H, scale, sumexp, targets, Pce, Pnv);
  k_out<<<1, 256, 0, stream>>>(Pspike, Pmem, Pce, Pnv, out);
}